// Round 1
// 821.822 us; speedup vs baseline: 1.0406x; 1.0406x over previous
//
#include <hip/hip_runtime.h>
#include <hip/hip_bf16.h>
#include <math.h>

// Problem constants (AttentionPool): B=8, N=4096, C=1536, H=24, hd=64, R=8
#define Bb 8
#define Nn 4096
#define Cc 1536
#define Hh 24
#define HD 64
#define RR 8
#define MKV (Bb * Nn)        // 32768 rows for K/V GEMM
#define NKV (2 * Cc)         // 3072 cols (K and V fused)
#define NCHUNK 16            // key chunks for split attention
#define CK 256               // keys per chunk

typedef unsigned short u16;
typedef unsigned int u32;
typedef __attribute__((ext_vector_type(2))) u32 u32x2;

typedef __attribute__((ext_vector_type(8))) short bf16x8;
typedef __attribute__((ext_vector_type(4))) float f32x4;

__device__ __forceinline__ u16 f32_to_bf16(float f) {
    union { float f; u32 u; } v; v.f = f;
    u32 r = v.u + 0x7fffu + ((v.u >> 16) & 1u);  // RNE
    return (u16)(r >> 16);
}
__device__ __forceinline__ float bflo(u32 p) {
    union { u32 u; float f; } v; v.u = p << 16; return v.f;
}
__device__ __forceinline__ float bfhi(u32 p) {
    union { u32 u; float f; } v; v.u = p & 0xffff0000u; return v.f;
}
__device__ __forceinline__ ushort4 cvt4(float4 v, float s) {
    ushort4 o;
    o.x = f32_to_bf16(v.x * s); o.y = f32_to_bf16(v.y * s);
    o.z = f32_to_bf16(v.z * s); o.w = f32_to_bf16(v.w * s);
    return o;
}

// ---------------- fused prep: casts + q gather + zero fills, one dispatch ----------------
__global__ __launch_bounds__(256)
void prep_kernel(const float* __restrict__ x,
                 const float* __restrict__ Wk, const float* __restrict__ Wv,
                 const float* __restrict__ Wq, const float* __restrict__ Wp,
                 u16* __restrict__ xb, u16* __restrict__ wkvb,
                 u16* __restrict__ wqb, u16* __restrict__ wpb,
                 u16* __restrict__ xqp, u16* __restrict__ aob,
                 float* __restrict__ dout)
{
    const int blk = blockIdx.x, tid = threadIdx.x;
    if (blk < 49152) {
        int i = blk * 256 + tid;                 // quad index < 12582912
        float4 v = ((const float4*)x)[i];
        ((ushort4*)xb)[i] = cvt4(v, 1.0f);
        int row = i / 384;                       // 384 quads per 1536-row
        int n = row & (Nn - 1);
        if (n < RR) {                            // q gather, SCALE=0.125 folded (exact)
            int b = row >> 12;
            int cq = i - row * 384;
            ((ushort4*)xqp)[(size_t)(b * RR + n) * 384 + cq] = cvt4(v, 0.125f);
        }
    } else if (blk < 58368) {
        int t = blk - 49152;
        int w = t / 2304;
        int i = (t - w * 2304) * 256 + tid;      // < 589824 quads
        const float4* src = (w == 0) ? (const float4*)Wk : (w == 1) ? (const float4*)Wv
                          : (w == 2) ? (const float4*)Wq : (const float4*)Wp;
        u16* dst = (w == 0) ? wkvb : (w == 1) ? wkvb + 2359296 : (w == 2) ? wqb : wpb;
        ((ushort4*)dst)[i] = cvt4(src[i], 1.0f);
    } else if (blk < 58464) {                    // zero xqp rows 64..127
        int i = (blk - 58368) * 256 + tid;
        ushort4 z = {0, 0, 0, 0};
        ((ushort4*)(xqp + 64 * Cc))[i] = z;
    } else if (blk < 58656) {                    // zero aob (all 128 rows)
        int i = (blk - 58464) * 256 + tid;
        ushort4 z = {0, 0, 0, 0};
        ((ushort4*)aob)[i] = z;
    } else {                                     // zero d_out (for split-K atomics)
        int i = (blk - 58656) * 256 + tid;
        float4 z = {0.f, 0.f, 0.f, 0.f};
        ((float4*)dout)[i] = z;
    }
}

// ---------------- OLD 128x128 GEMM body (kept for tiny output projection) ----------------
template <int OUT>
__device__ __forceinline__ void gemm_body64(
    const u16* __restrict__ A, const u16* __restrict__ B, void* __restrict__ Cv,
    const float* __restrict__ bias, int M_valid, int N, int K,
    int m0, int n0, int kbeg, int kend, u16* As, u16* Bs)
{
    const int tid = threadIdx.x;
    const int wave = tid >> 6, lane = tid & 63;
    const int wm = (wave & 1) * 64, wn = (wave >> 1) * 64;
    const int fm = lane & 15;
    const int kq = lane >> 4;            // 0..3

    f32x4 acc[4][4] = {};

    const u16* aptr[4]; const u16* bptr[4]; int ldsoff[4];
    #pragma unroll
    for (int off = 0; off < 4; ++off) {
        int e = tid * 8 + off * 2048;
        int r = e >> 6, cp = (e >> 3) & 7;
        int csrc = cp ^ (r & 7);
        aptr[off] = A + (size_t)(m0 + r) * K + csrc * 8;
        bptr[off] = B + (size_t)(n0 + r) * K + csrc * 8;
        ldsoff[off] = e;
    }

    for (int k0 = kbeg; k0 < kend; k0 += 64) {
        #pragma unroll
        for (int off = 0; off < 4; ++off)
            __builtin_amdgcn_global_load_lds(
                (const __attribute__((address_space(1))) void*)(aptr[off] + k0),
                (__attribute__((address_space(3))) void*)(As + ldsoff[off]), 16, 0, 0);
        #pragma unroll
        for (int off = 0; off < 4; ++off)
            __builtin_amdgcn_global_load_lds(
                (const __attribute__((address_space(1))) void*)(bptr[off] + k0),
                (__attribute__((address_space(3))) void*)(Bs + ldsoff[off]), 16, 0, 0);
        __syncthreads();

        #pragma unroll
        for (int ks = 0; ks < 2; ++ks) {
            bf16x8 af[4], bfr[4];
            #pragma unroll
            for (int i = 0; i < 4; ++i) {
                int r = wm + i * 16 + fm;
                int c = ks * 4 + kq;
                af[i] = *(const bf16x8*)&As[r * 64 + ((c ^ (r & 7)) << 3)];
            }
            #pragma unroll
            for (int j = 0; j < 4; ++j) {
                int r = wn + j * 16 + fm;
                int c = ks * 4 + kq;
                bfr[j] = *(const bf16x8*)&Bs[r * 64 + ((c ^ (r & 7)) << 3)];
            }
            #pragma unroll
            for (int i = 0; i < 4; ++i)
                #pragma unroll
                for (int j = 0; j < 4; ++j)
                    acc[i][j] = __builtin_amdgcn_mfma_f32_16x16x32_bf16(af[i], bfr[j], acc[i][j], 0, 0, 0);
        }
        __syncthreads();
    }

    const int col = lane & 15, rb = (lane >> 4) * 4;
    #pragma unroll
    for (int i = 0; i < 4; ++i)
        #pragma unroll
        for (int j = 0; j < 4; ++j)
            #pragma unroll
            for (int rg = 0; rg < 4; ++rg) {
                int m = m0 + wm + i * 16 + rb + rg;
                if (m < M_valid) {
                    int n = n0 + wn + j * 16 + col;
                    float v = acc[i][j][rg];
                    if (bias) v += bias[n];
                    size_t idx = (size_t)m * N + n;
                    if (OUT == 0)       ((float*)Cv)[idx] = v;
                    else if (OUT == 1)  ((u16*)Cv)[idx] = f32_to_bf16(v);
                    else                atomicAdd((float*)Cv + idx, v);
                }
            }
}

// ---------------- NEW: 256x256 8-phase GEMM body (T1+T2+T3/T4+T5 stack) ----------------
// C[M,N] = A[M,K]*B[N,K]^T. 512 threads = 8 waves (2M x 4N), per-wave 128x64 out.
// LDS: 2 bufs x {A,B} x {Khalf0,Khalf1}, each region [256 rows][32 elems] (64 B rows).
// Chunk swizzle within region row: 16B chunk c stored at c ^ ((row>>1)&3)
//   -> each quarter-wave's ds_read_b128 = 2 lanes/bank-group (free).
// Staged via global_load_lds with PRE-SWIZZLED global source (LDS dest linear).
// Schedule/iteration (2 K-tiles T=2it (buf0), T+1 (buf1); 4 MFMA-phases each):
//   p1: buf0/ks0/mfrags0-3 (+ldB)  stage (T+1)A-K1
//   p2: buf0/ks0/mfrags4-7         stage (T+1)B-K1
//   p3: buf0/ks1/mfrags0-3 (+ldB)  stage (T+2)A-K0
//   p4: buf0/ks1/mfrags4-7         stage (T+2)B-K0   vmcnt(4)
//   p5: buf1/ks0/mfrags0-3 (+ldB)  stage (T+2)A-K1
//   p6: buf1/ks0/mfrags4-7         stage (T+2)B-K1
//   p7: buf1/ks1/mfrags0-3 (+ldB)  stage (T+3)A-K0
//   p8: buf1/ks1/mfrags4-7         stage (T+3)B-K0   vmcnt(4)
// Counted vmcnt(4) leaves the 2 newest stage-pairs in flight; drains everything a
// subsequent phase reads. Last iteration: p3..p8 stages skipped, p4 uses vmcnt(0)
// (p1/p2 staged the final tile's K1 and must drain before p7/p8 read it).
#define STG(MAT, BUF, KS, KOFF) do {                                                   \
    const u16* _s0 = ((MAT) == 0 ? sA0 : sB0) + (KOFF);                                \
    const u16* _s1 = ((MAT) == 0 ? sA1 : sB1) + (KOFF);                                \
    u16* _d = lds + (BUF) * 32768 + (MAT) * 16384 + (KS) * 8192;                       \
    __builtin_amdgcn_global_load_lds(                                                  \
        (const __attribute__((address_space(1))) void*)_s0,                            \
        (__attribute__((address_space(3))) void*)(_d + dst0), 16, 0, 0);               \
    __builtin_amdgcn_global_load_lds(                                                  \
        (const __attribute__((address_space(1))) void*)_s1,                            \
        (__attribute__((address_space(3))) void*)(_d + dst1), 16, 0, 0);               \
} while (0)

#define PH(BUF, KS, MH, DOB, STG_STMT, VW) do {                                        \
    if (DOB) {                                                                         \
        _Pragma("unroll")                                                              \
        for (int j = 0; j < 4; ++j)                                                    \
            bfr[j] = *(const bf16x8*)(lds + (BUF) * 32768 + 16384 + (KS) * 8192        \
                                          + bRd + j * 512);                            \
    }                                                                                  \
    _Pragma("unroll")                                                                  \
    for (int ii = 0; ii < 4; ++ii)                                                     \
        af[ii] = *(const bf16x8*)(lds + (BUF) * 32768 + (KS) * 8192                    \
                                      + aRd + ((MH) + ii) * 512);                      \
    STG_STMT;                                                                          \
    __builtin_amdgcn_s_barrier();                                                      \
    asm volatile("s_waitcnt lgkmcnt(0)" ::: "memory");                                 \
    __builtin_amdgcn_sched_barrier(0);                                                 \
    __builtin_amdgcn_s_setprio(1);                                                     \
    _Pragma("unroll")                                                                  \
    for (int ii = 0; ii < 4; ++ii)                                                     \
        _Pragma("unroll")                                                              \
        for (int j = 0; j < 4; ++j)                                                    \
            acc[(MH) + ii][j] = __builtin_amdgcn_mfma_f32_16x16x32_bf16(               \
                af[ii], bfr[j], acc[(MH) + ii][j], 0, 0, 0);                            \
    __builtin_amdgcn_s_setprio(0);                                                     \
    VW;                                                                                \
    __builtin_amdgcn_s_barrier();                                                      \
} while (0)

template <int OUT>
__device__ __forceinline__ void gemm256_body(
    const u16* __restrict__ A, const u16* __restrict__ B, void* __restrict__ Cv,
    int M_valid, int N, int K, int m0, int n0, u16* lds)
{
    const int tid = threadIdx.x;
    const int lane = tid & 63;
    const int w = tid >> 6;
    const int wr = w >> 2, wc = w & 3;           // wave grid 2M x 4N
    const int fm = lane & 15, kq = lane >> 4;

    // staging: thread t covers region row (t>>2) [+128 for inst1], chunk t&3.
    // data at (r, c') came from source chunk c' ^ ((r>>1)&3); (r>>1)&3 == (t>>3)&3
    // for both insts (rows differ by 128 -> same &3).
    const int ra = tid >> 2;
    const int csrc = (tid & 3) ^ ((tid >> 3) & 3);
    const u16* sA0 = A + (size_t)(m0 + ra) * K + csrc * 8;
    const u16* sA1 = A + (size_t)(m0 + 128 + ra) * K + csrc * 8;
    const u16* sB0 = B + (size_t)(n0 + ra) * K + csrc * 8;
    const u16* sB1 = B + (size_t)(n0 + 128 + ra) * K + csrc * 8;
    const int dst0 = tid * 8, dst1 = 4096 + tid * 8;   // elems (16 B / thread)

    // ds_read bases (elems). Row R = wbase + frag*16 + fm; (R>>1)&3 == (fm>>1)&3.
    const int swz = (fm >> 1) & 3;
    const int aRd = (wr * 128 + fm) * 32 + ((kq ^ swz) << 3);
    const int bRd = (wc * 64 + fm) * 32 + ((kq ^ swz) << 3);

    f32x4 acc[8][4] = {};
    bf16x8 af[4], bfr[4];

    // prologue: T0 {A-K0,B-K0,A-K1,B-K1}, T1 {A-K0,B-K0}; drain T0, keep T1 in flight
    STG(0, 0, 0, 0);
    STG(1, 0, 0, 0);
    STG(0, 0, 1, 32);
    STG(1, 0, 1, 32);
    STG(0, 1, 0, 64);
    STG(1, 1, 0, 64);
    asm volatile("s_waitcnt vmcnt(4)" ::: "memory");
    __builtin_amdgcn_s_barrier();

    const int NITER = K >> 7;                    // 2 K-tiles (BK=64) per iteration
    #pragma unroll 1
    for (int it = 0; it < NITER; ++it) {
        const int kT1 = (it * 2 + 1) * 64;
        const int kT2 = kT1 + 64, kT3 = kT1 + 128;
        const bool ok = (it < NITER - 1);
        PH(0, 0, 0, true,  STG(0, 1, 1, kT1 + 32), );
        PH(0, 0, 4, false, STG(1, 1, 1, kT1 + 32), );
        PH(0, 1, 0, true,  if (ok) STG(0, 0, 0, kT2), );
        PH(0, 1, 4, false, if (ok) STG(1, 0, 0, kT2),
           if (ok) { asm volatile("s_waitcnt vmcnt(4)" ::: "memory"); }
           else    { asm volatile("s_waitcnt vmcnt(0)" ::: "memory"); } );
        PH(1, 0, 0, true,  if (ok) STG(0, 0, 1, kT2 + 32), );
        PH(1, 0, 4, false, if (ok) STG(1, 0, 1, kT2 + 32), );
        PH(1, 1, 0, true,  if (ok) STG(0, 1, 0, kT3), );
        PH(1, 1, 4, false, if (ok) STG(1, 1, 0, kT3),
           if (ok) { asm volatile("s_waitcnt vmcnt(4)" ::: "memory"); } );
    }

    // C/D layout: col = lane&15, row = (lane>>4)*4 + reg  [m89, verified]
    const int col = lane & 15, rb2 = (lane >> 4) * 4;
    #pragma unroll
    for (int ii = 0; ii < 8; ++ii)
        #pragma unroll
        for (int j = 0; j < 4; ++j)
            #pragma unroll
            for (int rg = 0; rg < 4; ++rg) {
                int m = m0 + wr * 128 + ii * 16 + rb2 + rg;
                if (m < M_valid) {
                    int n = n0 + wc * 64 + j * 16 + col;
                    float v = acc[ii][j][rg];
                    size_t idx = (size_t)m * N + n;
                    if (OUT == 0) ((float*)Cv)[idx] = v;
                    else          ((u16*)Cv)[idx] = f32_to_bf16(v);
                }
            }
}

// blocks 0..1535: KV proj, XCD-swizzled (1536 % 8 == 0, bijective), n fastest per XCD.
// blocks 1536..1541: q proj (M padded; rows 128..255 read adjacent ws garbage, unstored).
__global__ __launch_bounds__(512, 2)
void gemm_main(const u16* __restrict__ xqp, const u16* __restrict__ wqb,
               float* __restrict__ qout,
               const u16* __restrict__ xb, const u16* __restrict__ wkvb,
               u16* __restrict__ kvb)
{
    __shared__ u16 lds[65536];                   // 128 KiB
    const int blk = blockIdx.x;
    if (blk < 1536) {
        int g = blk & 7, s = blk >> 3;           // 192 blocks per XCD class
        int mb = g * 16 + s / 12, nb = s % 12;
        gemm256_body<1>(xb, wkvb, kvb, MKV, NKV, Cc, mb * 256, nb * 256, lds);
    } else {
        int nb = blk - 1536;
        gemm256_body<0>(xqp, wqb, qout, 64, Cc, Cc, 0, nb * 256, lds);
    }
}

// ---------------- output projection, split-K x4 with f32 atomics (old 128^2 body) -------
__global__ __launch_bounds__(256, 3)
void gemm_out(const u16* __restrict__ aob, const u16* __restrict__ wpb,
              float* __restrict__ out, const float* __restrict__ bp)
{
    __shared__ u16 As[128 * 64];
    __shared__ u16 Bs[128 * 64];
    const int nb = blockIdx.x;                   // 0..11
    const int z = blockIdx.y;                    // 0..3
    gemm_body64<2>(aob, wpb, out, (z == 0) ? bp : nullptr,
                   64, Cc, Cc, 0, nb * 128, z * 384, (z + 1) * 384, As, Bs);
}

// ---------------- split attention: grid (NCHUNK, B*H), 256 keys per block ----------------
__global__ __launch_bounds__(256)
void attn_part_kernel(const float* __restrict__ qout, const u16* __restrict__ kv,
                      const int* __restrict__ mask,
                      float* __restrict__ opart, float* __restrict__ mstat,
                      float* __restrict__ lstat)
{
    const int chunk = blockIdx.x;       // 0..15
    const int bh = blockIdx.y;          // 0..191
    const int b = bh / Hh, h = bh - b * Hh;
    const int tid = threadIdx.x;

    __shared__ u16  Vs[CK * HD];        // 32 KB
    __shared__ float Ps[RR][CK];        // 8 KB
    __shared__ float qs[RR * HD];       // 2 KB

    for (int i = tid; i < RR * HD; i += 256)
        qs[i] = qout[(size_t)(b * RR + (i >> 6)) * Cc + h * HD + (i & 63)];
    __syncthreads();

    // V-chunk DMA (overlaps QK^T; drained by the next barrier)
    {
        const u16* vsrc = kv + (size_t)(b * Nn + chunk * CK) * NKV + Cc + h * HD;
        const int vr = tid >> 3, vc = (tid & 7) * 8;
        #pragma unroll
        for (int i = 0; i < 8; ++i) {
            __builtin_amdgcn_global_load_lds(
                (const __attribute__((address_space(1))) void*)(vsrc + (size_t)(i * 32 + vr) * NKV + vc),
                (__attribute__((address_space(3))) void*)(Vs + i * 2048 + tid * 8), 16, 0, 0);
        }
    }

    // phase A: thread = key; masked scores
    {
        const int j = chunk * CK + tid;
        float s[RR] = {0, 0, 0, 0, 0, 0, 0, 0};
        const u16* krow = kv + (size_t)(b * Nn + j) * NKV + h * HD;
        #pragma unroll
        for (int c = 0; c < 8; ++c) {
            uint4 kvec = *(const uint4*)(krow + c * 8);
            float kf0 = bflo(kvec.x), kf1 = bfhi(kvec.x);
            float kf2 = bflo(kvec.y), kf3 = bfhi(kvec.y);
            float kf4 = bflo(kvec.z), kf5 = bfhi(kvec.z);
            float kf6 = bflo(kvec.w), kf7 = bfhi(kvec.w);
            #pragma unroll
            for (int r = 0; r < RR; ++r) {
                const float4 qa = *(const float4*)&qs[r * HD + c * 8];
                const float4 qb = *(const float4*)&qs[r * HD + c * 8 + 4];
                s[r] += qa.x * kf0 + qa.y * kf1 + qa.z * kf2 + qa.w * kf3
                      + qb.x * kf4 + qb.y * kf5 + qb.z * kf6 + qb.w * kf7;
            }
        }
        #pragma unroll
        for (int r = 0; r < RR; ++r) {
            bool keep = (j < RR) ? (j == r)
                                 : (mask[(size_t)(b * RR + r) * (Nn - RR) + (j - RR)] != 0);
            Ps[r][tid] = keep ? s[r] : -INFINITY;
        }
    }
    __syncthreads();

    // phase A2: per-row chunk max & exp-sum
    {
        const int r = tid >> 5, g = tid & 31;
        float vals[CK / 32];
        float mx = -INFINITY;
        #pragma unroll
        for (int i = 0; i < CK / 32; ++i) {
            vals[i] = Ps[r][g + 32 * i];
            mx = fmaxf(mx, vals[i]);
        }
        #pragma unroll
        for (int m = 16; m >= 1; m >>= 1) mx = fmaxf(mx, __shfl_xor(mx, m));
        const float mfin = fmaxf(mx, -1e30f);
        float sum = 0.f;
        #pragma unroll
        for (int i = 0; i < CK / 32; ++i) {
            float e = __expf(vals[i] - mfin);
            Ps[r][g + 32 * i] = e;
            sum += e;
        }
        #pragma unroll
        for (int m = 16; m >= 1; m >>= 1) sum += __shfl_xor(sum, m);
        if (g == 0) {
            size_t si = ((size_t)bh * NCHUNK + chunk) * RR + r;
            mstat[si] = mx;
            lstat[si] = sum;
        }
    }
    __syncthreads();

    // phase B: o[r,d] = sum_k P[r,k] * V[k,d]
    {
        const int r  = tid >> 5;
        const int g  = tid & 31;
        const int kh = g >> 4;
        const int d4 = (g & 15) * 4;
        float a0 = 0.f, a1 = 0.f, a2 = 0.f, a3 = 0.f;
        const float* pr = &Ps[r][kh * 128];
        const u16* vb = Vs + kh * 128 * HD + d4;
        #pragma unroll 2
        for (int k4 = 0; k4 < 32; ++k4) {
            f32x4 pv = *(const f32x4*)(pr + k4 * 4);
            #pragma unroll
            for (int t = 0; t < 4; ++t) {
                float p = pv[t];
                u32x2 vv = *(const u32x2*)(vb + (k4 * 4 + t) * HD);
                a0 += p * bflo(vv.x); a1 += p * bfhi(vv.x);
                a2 += p * bflo(vv.y); a3 += p * bfhi(vv.y);
            }
        }
        a0 += __shfl_xor(a0, 16); a1 += __shfl_xor(a1, 16);
        a2 += __shfl_xor(a2, 16); a3 += __shfl_xor(a3, 16);
        if (kh == 0) {
            size_t po = ((size_t)bh * NCHUNK + chunk) * (RR * HD) + r * HD + d4;
            float4 o = {a0, a1, a2, a3};
            *(float4*)(opart + po) = o;
        }
    }
}

// ---------------- combine partials -> bf16 attention output ----------------
__global__ __launch_bounds__(256)
void attn_combine_kernel(const float* __restrict__ opart, const float* __restrict__ mstat,
                         const float* __restrict__ lstat, u16* __restrict__ aob)
{
    int idx = blockIdx.x * 256 + threadIdx.x;   // < 64*1536
    int row = idx / Cc, col = idx - row * Cc;
    int b = row >> 3, r = row & 7;
    int h = col >> 6, d = col & 63;
    int bh = b * Hh + h;
    float M = -INFINITY;
    #pragma unroll
    for (int c = 0; c < NCHUNK; ++c)
        M = fmaxf(M, mstat[((size_t)bh * NCHUNK + c) * RR + r]);
    float L = 0.f, O = 0.f;
    #pragma unroll
    for (int c = 0; c < NCHUNK; ++c) {
        size_t si = ((size_t)bh * NCHUNK + c) * RR + r;
        float w = __expf(mstat[si] - M);
        L += w * lstat[si];
        O += w * opart[((size_t)bh * NCHUNK + c) * (RR * HD) + r * HD + d];
    }
    aob[(size_t)row * Cc + col] = f32_to_bf16(O / L);
}

// ---------------- launch ----------------
extern "C" void kernel_launch(void* const* d_in, const int* in_sizes, int n_in,
                              void* d_out, int out_size, void* d_ws, size_t ws_size,
                              hipStream_t stream)
{
    const float* x    = (const float*)d_in[0];
    const int*   mask = (const int*)d_in[1];
    const float* Wq   = (const float*)d_in[2];
    const float* Wk   = (const float*)d_in[3];
    const float* Wv   = (const float*)d_in[4];
    const float* Wp   = (const float*)d_in[5];
    const float* bp   = (const float*)d_in[6];

    char* ws = (char*)d_ws;
    u16*   xb     = (u16*)(ws);                       // 100,663,296  x bf16 [32768,1536]
    u16*   wkvb   = (u16*)(ws + 100663296);           //   9,437,184  [Wk;Wv] bf16 [3072,1536]
    u16*   wqb    = (u16*)(ws + 110100480);           //   4,718,592  Wq bf16
    u16*   wpb    = (u16*)(ws + 114819072);           //   4,718,592  Wp bf16
    u16*   kvb    = (u16*)(ws + 119537664);           // 201,326,592  kv bf16 [32768,3072]
    u16*   xqp    = (u16*)(ws + 320864256);           //     393,216  q input padded [128,1536]
    float* qout   = (float*)(ws + 321257472);         //     786,432  q proj f32 [128,1536]
    u16*   aob    = (u16*)(ws + 322043904);           //     393,216  attn out padded [128,1536]
    // partials alias xb (dead after KV GEMM)
    float* opart  = (float*)(ws);                     // 6,291,456 B
    float* mstat  = (float*)(ws + 6291456);           // 98,304 B
    float* lstat  = (float*)(ws + 6389760);           // 98,304 B

    // 1: all casts + q gather + zero fills
    prep_kernel<<<58752, 256, 0, stream>>>(x, Wk, Wv, Wq, Wp, xb, wkvb, wqb, wpb,
                                           xqp, aob, (float*)d_out);
    // 2: fused K/V proj (256^2 8-phase, blocks 0..1535) + q proj (blocks 1536..1541)
    gemm_main<<<1542, 512, 0, stream>>>(xqp, wqb, qout, xb, wkvb, kvb);
    // 3: split attention
    attn_part_kernel<<<dim3(NCHUNK, Bb * Hh), 256, 0, stream>>>(qout, kvb, mask,
                                                                opart, mstat, lstat);
    // 4: combine
    attn_combine_kernel<<<384, 256, 0, stream>>>(opart, mstat, lstat, aob);
    // 5: output projection, split-K atomics (d_out zeroed by prep)
    gemm_out<<<dim3(12, 4), 256, 0, stream>>>(aob, wpb, (float*)d_out, bp);
}